// Round 11
// baseline (2611.466 us; speedup 1.0000x reference)
//
#include <hip/hip_runtime.h>
#include <hip/hip_bf16.h>
#include <stdint.h>

#define D_DIM 1024
#define N_DIM 4096
#define C_CLS 10
#define L_IT 8
#define M_DIM 11264   // (C+1)*D
#define NBM 44        // M_DIM / 256

typedef __bf16 bf16_t;
typedef __bf16 bf16x8 __attribute__((ext_vector_type(8)));
typedef __bf16 bf16x4 __attribute__((ext_vector_type(4)));
typedef float  f32x4  __attribute__((ext_vector_type(4)));
typedef float  f32x16 __attribute__((ext_vector_type(16)));
typedef unsigned short u16x8 __attribute__((ext_vector_type(8)));

__device__ __forceinline__ float bf2f(uint16_t u) {
  union { uint32_t i; float f; } x; x.i = ((uint32_t)u) << 16; return x.f;
}

// ---------------- pack W = [Cs ; E] fp32 -> bf16 ----------------
__global__ __launch_bounds__(256) void pack_w(const float4* __restrict__ Cs,
                                              const float4* __restrict__ El,
                                              bf16x4* __restrict__ dst) {
  const int CS4 = C_CLS * D_DIM * D_DIM / 4;
  int i = blockIdx.x * 256 + threadIdx.x;
  float4 v = (i < CS4) ? Cs[i] : El[i - CS4];
  bf16x4 o;
  o[0] = (bf16_t)v.x; o[1] = (bf16_t)v.y; o[2] = (bf16_t)v.z; o[3] = (bf16_t)v.w;
  dst[i] = o;
}

// ---------------- layer-0 init ----------------
__global__ __launch_bounds__(256) void init_zt(const float* __restrict__ Zin,
                                               float* __restrict__ ZfT,
                                               bf16_t* __restrict__ ZbT) {
  __shared__ float tile[32][33];
  int tx = threadIdx.x & 31, ty = threadIdx.x >> 5;
  int nb = blockIdx.x, db = blockIdx.y;
  int n = nb * 32 + tx;
#pragma unroll
  for (int j = 0; j < 32; j += 8) {
    int d = db * 32 + ty + j;
    tile[ty + j][tx] = Zin[(size_t)d * N_DIM + n];
  }
  __syncthreads();
  int d2 = db * 32 + tx;
#pragma unroll
  for (int j = 0; j < 32; j += 8) {
    int n2 = nb * 32 + ty + j;
    float v = tile[tx][ty + j];
    ZfT[(size_t)n2 * D_DIM + d2] = v;
    ZbT[(size_t)n2 * D_DIM + d2] = (bf16_t)v;
  }
}

// ---------------- final transpose-out ----------------
__global__ __launch_bounds__(256) void final_out(const float* __restrict__ ZfT,
                                                 float* __restrict__ outp) {
  __shared__ float tile[32][33];
  int tx = threadIdx.x & 31, ty = threadIdx.x >> 5;
  int nb = blockIdx.x, db = blockIdx.y;
#pragma unroll
  for (int j = 0; j < 32; j += 8) {
    int n = nb * 32 + ty + j;
    int d = db * 32 + tx;
    tile[ty + j][tx] = ZfT[(size_t)n * D_DIM + d];
  }
  __syncthreads();
#pragma unroll
  for (int j = 0; j < 32; j += 8) {
    int d2 = db * 32 + ty + j;
    int n2 = nb * 32 + tx;
    outp[(size_t)d2 * N_DIM + n2] = tile[tx][ty + j];
  }
}

// ================= 256x256 GEMM — m201 8-phase template, 32x32x16 MFMA =================
// OUT_T[col][row] = (Wb * ZbT^T)^T. 512 thr = 8 waves (2Mx4N), BK=64, K=1024 (16 K-tiles).
// Same phase/stage/vmcnt structure as r10; MFMA shape 32x32x16 (20% better cy/FLOP, m119).
// Per phase: one (qm x qn) quadrant x K=64 = 8 MFMA/wave; reads 12/4/8/0 per phase.

#define SA(buf, h, t) do {                                                              \
    _Pragma("unroll") for (int e_ = 0; e_ < 2; ++e_) {                                  \
      const bf16_t* s_ = Wb + aoff0[e_] + (size_t)(h) * 65536 + (size_t)(t) * 64;       \
      __builtin_amdgcn_global_load_lds(                                                 \
        (const __attribute__((address_space(1))) void*)s_,                              \
        (__attribute__((address_space(3))) void*)(lds + (buf)*16384 + (h)*8192 + dstslot[e_]), \
        16, 0, 0);                                                                      \
    } } while (0)

#define SBst(buf, h, t) do {                                                            \
    _Pragma("unroll") for (int e_ = 0; e_ < 2; ++e_) {                                  \
      const bf16_t* s_ = ZbT + boff0[e_] + (size_t)(h) * 32768 + (size_t)(t) * 64;      \
      __builtin_amdgcn_global_load_lds(                                                 \
        (const __attribute__((address_space(1))) void*)s_,                              \
        (__attribute__((address_space(3))) void*)(lds + 32768 + (buf)*16384 + (h)*8192 + dstslot[e_]), \
        16, 0, 0);                                                                      \
    } } while (0)

// A reads for one qm half: mf 0..1, kstep 0..3 (8 x b128)
#define LOAD_A(buf, qm) do {                                                            \
    _Pragma("unroll") for (int mf_ = 0; mf_ < 2; ++mf_)                                 \
      _Pragma("unroll") for (int k_ = 0; k_ < 4; ++k_)                                  \
        a[mf_][k_] = *(const bf16x8*)(lds + (buf)*16384 + (qm)*8192 + aRowBase + mf_*2048 + sidx[k_]); \
  } while (0)

// B reads for one qn half: kstep 0..3 (4 x b128)
#define LOAD_Bq(buf, qn, arr) do {                                                      \
    _Pragma("unroll") for (int k_ = 0; k_ < 4; ++k_)                                    \
      arr[k_] = *(const bf16x8*)(lds + 32768 + (buf)*16384 + (qn)*8192 + bRowBase + sidx[k_]); \
  } while (0)

// 8 MFMA: 2 mf x 4 ksteps, acc[qm*2+mf][qn]
#define MFMAQ(qm, qn, arr) do {                                                         \
    _Pragma("unroll") for (int mf_ = 0; mf_ < 2; ++mf_)                                 \
      _Pragma("unroll") for (int k_ = 0; k_ < 4; ++k_)                                  \
        acc[(qm)*2+mf_][qn] = __builtin_amdgcn_mfma_f32_32x32x16_bf16(                  \
            a[mf_][k_], arr[k_], acc[(qm)*2+mf_][qn], 0, 0, 0);                         \
  } while (0)

#define BAR   __builtin_amdgcn_s_barrier()
#define VM(n) asm volatile("s_waitcnt vmcnt(" #n ")" ::: "memory")
#define LGKM8 asm volatile("s_waitcnt lgkmcnt(8)" ::: "memory")
#define PRIO1 __builtin_amdgcn_s_setprio(1)
#define PRIO0 __builtin_amdgcn_s_setprio(0)

#define PH8(qm, qn, arr, LOADS, STAGES, PREBAR, POSTMFMA) do {                          \
    LOADS;                                                                              \
    STAGES;                                                                             \
    PREBAR;                                                                             \
    BAR;                                                                                \
    asm volatile("s_waitcnt lgkmcnt(0)" ::: "memory");                                  \
    PRIO1;                                                                              \
    MFMAQ(qm, qn, arr);                                                                 \
    PRIO0;                                                                              \
    POSTMFMA;                                                                           \
    BAR;                                                                                \
  } while (0)

// shared body for production + diagnostics
#define GEMM_PRE()                                                                      \
  int tid = threadIdx.x;                                                                \
  int wave = tid >> 6, lane = tid & 63;                                                 \
  int wrow = wave >> 2, wcol = wave & 3;                                                \
  int l31 = lane & 31, hi = lane >> 5;                                                  \
  int sw = l31 & 7;                                                                     \
  size_t aoff0[2], boff0[2];                                                            \
  int dstslot[2];                                                                       \
  _Pragma("unroll") for (int e = 0; e < 2; ++e) {                                       \
    int j = e * 512 + tid;                                                              \
    int rih = j >> 3, sl = j & 7;                                                       \
    int sg = sl ^ (rih & 7);                                                            \
    int arow = (rih & 63) + ((rih >> 6) << 7);                                          \
    int brow = (rih & 31) + ((rih >> 5) << 6);                                          \
    aoff0[e] = (size_t)(m0 + arow) * 1024 + sg * 8;                                     \
    boff0[e] = (size_t)(n0 + brow) * 1024 + sg * 8;                                     \
    dstslot[e] = e * 4096 + wave * 512;                                                 \
  }                                                                                     \
  int aRowBase = (wrow * 64 + l31) * 64;                                                \
  int bRowBase = (wcol * 32 + l31) * 64;                                                \
  int sidx[4];                                                                          \
  _Pragma("unroll") for (int k = 0; k < 4; ++k) sidx[k] = ((k * 2 + hi) ^ sw) * 8;      \
  f32x16 acc[4][2] = {};                                                                \
  bf16x8 a[2][4], b0[4], b1[4];

#define GEMM_KLOOP(STG)                                                                 \
  for (int it = 0; it < 8; ++it) {                                                      \
    int tO = 2 * it + 1, tN = 2 * it + 2, tM = 2 * it + 3;                              \
    bool st = (it < 7) && STG;                                                          \
    PH8(0, 0, b0, LOAD_A(0, 0); LOAD_Bq(0, 0, b0), { if (STG) SA(1, 1, tO); }, LGKM8, );\
    PH8(0, 1, b1, LOAD_Bq(0, 1, b1), { if (st) SA(0, 0, tN); }, , );                    \
    PH8(1, 0, b0, LOAD_A(0, 1), { if (st) SBst(0, 0, tN); }, , );                       \
    PH8(1, 1, b1, , { if (st) SBst(0, 1, tN); }, ,                                      \
        { if (STG) { if (st) { VM(6); } else { VM(0); } } });                           \
    PH8(0, 0, b0, LOAD_A(1, 0); LOAD_Bq(1, 0, b0), { if (st) SA(0, 1, tN); }, LGKM8, ); \
    PH8(0, 1, b1, LOAD_Bq(1, 1, b1), { if (st) SA(1, 0, tM); }, , );                    \
    PH8(1, 0, b0, LOAD_A(1, 1), { if (st) SBst(1, 0, tM); }, , );                       \
    PH8(1, 1, b1, , { if (st) SBst(1, 1, tM); }, , { if (st) VM(6); });                 \
  }

#define GEMM_EPI(OUTP, SSQP, LDN)                                                       \
  _Pragma("unroll") for (int mg = 0; mg < 4; ++mg)                                      \
    _Pragma("unroll") for (int ng = 0; ng < 2; ++ng) {                                  \
      int col = n0 + wcol * 64 + ng * 32 + l31;                                         \
      _Pragma("unroll") for (int g = 0; g < 4; ++g) {                                   \
        int row = m0 + wrow * 128 + mg * 32 + g * 8 + hi * 4;                           \
        bf16x4 v;                                                                       \
        _Pragma("unroll") for (int rr = 0; rr < 4; ++rr)                                \
          v[rr] = (bf16_t)acc[mg][ng][g * 4 + rr];                                      \
        *(bf16x4*)((OUTP) + (size_t)col * M_DIM + row) = v;                             \
      }                                                                                 \
    }                                                                                   \
  if (m0 < C_CLS * 1024) {                                                              \
    int c = m0 >> 10;                                                                   \
    _Pragma("unroll") for (int ng = 0; ng < 2; ++ng) {                                  \
      float v = 0.f;                                                                    \
      _Pragma("unroll") for (int mg = 0; mg < 4; ++mg)                                  \
        _Pragma("unroll") for (int rr = 0; rr < 16; ++rr)                               \
          v += acc[mg][ng][rr] * acc[mg][ng][rr];                                       \
      v += __shfl_xor(v, 32);                                                           \
      if (hi == 0)                                                                      \
        atomicAdd(&(SSQP)[(size_t)c * (LDN) + n0 + wcol * 64 + ng * 32 + l31], v);      \
    }                                                                                   \
  }

__global__ __launch_bounds__(512, 2) void gemm_wz8(const bf16_t* __restrict__ Wb,
                                                   const bf16_t* __restrict__ ZbT,
                                                   bf16_t* __restrict__ OUT_T, int ldn,
                                                   float* __restrict__ ssq) {
  __shared__ __align__(16) bf16_t lds[65536];
  int nwg = gridDim.x, bid = blockIdx.x;
  int q = nwg >> 3, r = nwg & 7;
  int xcd = bid & 7, idx = bid >> 3;
  int swz = (xcd < r ? xcd * (q + 1) : r * (q + 1) + (xcd - r) * q) + idx;
  int m0 = (swz % NBM) * 256, n0 = (swz / NBM) * 256;

  GEMM_PRE();

  // prologue: E0.{A0,B0,B1,A1} + O0.{A0,B0,B1}; vmcnt(6) completes E0.
  SA(0, 0, 0); SBst(0, 0, 0); SBst(0, 1, 0); SA(0, 1, 0);
  SA(1, 0, 1); SBst(1, 0, 1); SBst(1, 1, 1);
  VM(6);
  BAR;

  GEMM_KLOOP(true);
  GEMM_EPI(OUT_T, ssq, ldn);
}

// ---------------- diagnostics (run once, outputs to dead ws regions) ----------------
__global__ __launch_bounds__(512, 2) void gemm_diag_full(const bf16_t* __restrict__ Wb,
                                                         const bf16_t* __restrict__ ZbT,
                                                         bf16_t* __restrict__ OUT_T,
                                                         float* __restrict__ ssq) {
  __shared__ __align__(16) bf16_t lds[65536];
  int bid = blockIdx.x;
  int m0 = (bid % NBM) * 256, n0 = (bid / NBM) * 256;
  GEMM_PRE();
  SA(0, 0, 0); SBst(0, 0, 0); SBst(0, 1, 0); SA(0, 1, 0);
  SA(1, 0, 1); SBst(1, 0, 1); SBst(1, 1, 1);
  VM(6);
  BAR;
  for (int rep = 0; rep < 24; ++rep) {
    GEMM_KLOOP(true);
    // re-prime pipeline for next rep (same data)
    if (rep < 23) {
      SA(0, 0, 0); SBst(0, 0, 0); SBst(0, 1, 0); SA(0, 1, 0);
      SA(1, 0, 1); SBst(1, 0, 1); SBst(1, 1, 1);
      VM(6);
      BAR;
    }
  }
  GEMM_EPI(OUT_T, ssq, N_DIM);
}

__global__ __launch_bounds__(512, 2) void gemm_diag_nostage(const bf16_t* __restrict__ Wb,
                                                            const bf16_t* __restrict__ ZbT,
                                                            bf16_t* __restrict__ OUT_T,
                                                            float* __restrict__ ssq) {
  __shared__ __align__(16) bf16_t lds[65536];
  int bid = blockIdx.x;
  int m0 = (bid % NBM) * 256, n0 = (bid / NBM) * 256;
  GEMM_PRE();
  (void)aoff0; (void)boff0; (void)dstslot;
  BAR;
  for (int rep = 0; rep < 24; ++rep) {
    GEMM_KLOOP(false);
  }
  GEMM_EPI(OUT_T, ssq, N_DIM);
}

// ---------------- fused softmax + update + normalize + ZbT emit ----------------
__global__ __launch_bounds__(256) void update2(const bf16_t* __restrict__ OUT_T, int Nc,
                                               const float* __restrict__ ssq,
                                               const float* __restrict__ gamma,
                                               const float* __restrict__ etap,
                                               const float* __restrict__ tempr,
                                               float* __restrict__ ZfT,
                                               bf16_t* __restrict__ ZbT,
                                               int n_off) {
  int wv = threadIdx.x >> 6, lane = threadIdx.x & 63;
  int nl = blockIdx.x * 4 + wv;
  if (nl >= Nc) return;
  int n = n_off + nl;
  float eta = etap[0], invT = 1.0f / tempr[0];

  float s[C_CLS], m = -1e30f;
#pragma unroll
  for (int c = 0; c < C_CLS; ++c) {
    float sim = -sqrtf(ssq[(size_t)c * Nc + nl]);
    s[c] = sim;
    m = fmaxf(m, sim);
  }
  float sum = 0.f;
#pragma unroll
  for (int c = 0; c < C_CLS; ++c) {
    float e = __expf((s[c] - m) * invT);
    s[c] = e;
    sum += e;
  }
  float invsum = 1.0f / sum;
  float gP[C_CLS];
#pragma unroll
  for (int c = 0; c < C_CLS; ++c) gP[c] = gamma[c] * s[c] * invsum;

  const u16x8* ob = (const u16x8*)(OUT_T + (size_t)nl * M_DIM) + lane * 2;
  float term[16] = {};
#pragma unroll
  for (int c = 0; c < C_CLS; ++c) {
    u16x8 v0 = ob[c * 128], v1 = ob[c * 128 + 1];
#pragma unroll
    for (int j = 0; j < 8; ++j) {
      term[j]     += gP[c] * bf2f(v0[j]);
      term[8 + j] += gP[c] * bf2f(v1[j]);
    }
  }
  u16x8 g0 = ob[C_CLS * 128], g1 = ob[C_CLS * 128 + 1];

  const f32x4* zp = (const f32x4*)(ZfT + (size_t)n * D_DIM) + lane * 4;
  f32x4 z[4] = { zp[0], zp[1], zp[2], zp[3] };

  float zn[16];
  float ss = 0.f;
#pragma unroll
  for (int j = 0; j < 16; ++j) {
    float g = bf2f(j < 8 ? g0[j & 7] : g1[j & 7]);
    float v = z[j >> 2][j & 3] + eta * (g - term[j]);
    zn[j] = v;
    ss += v * v;
  }
#pragma unroll
  for (int k = 1; k < 64; k <<= 1) ss += __shfl_xor(ss, k);
  float inv = rsqrtf(ss);

  f32x4* zo = (f32x4*)(ZfT + (size_t)n * D_DIM) + lane * 4;
  bf16x8* bo = (bf16x8*)(ZbT + (size_t)n * D_DIM) + lane * 2;
#pragma unroll
  for (int q4 = 0; q4 < 4; ++q4) {
    f32x4 o;
#pragma unroll
    for (int j = 0; j < 4; ++j) o[j] = zn[q4 * 4 + j] * inv;
    zo[q4] = o;
  }
#pragma unroll
  for (int h = 0; h < 2; ++h) {
    bf16x8 o;
#pragma unroll
    for (int j = 0; j < 8; ++j) o[j] = (bf16_t)(zn[h * 8 + j] * inv);
    bo[h] = o;
  }
}

extern "C" void kernel_launch(void* const* d_in, const int* in_sizes, int n_in,
                              void* d_out, int out_size, void* d_ws, size_t ws_size,
                              hipStream_t stream) {
  (void)in_sizes; (void)n_in; (void)out_size;
  const float* Zin        = (const float*)d_in[0];
  const float* Elist      = (const float*)d_in[1];
  const float* Cslist     = (const float*)d_in[2];
  const float* gamma      = (const float*)d_in[3];
  const float* eta        = (const float*)d_in[4];
  const float* temperature= (const float*)d_in[5];

  auto align256 = [](size_t x) { return (x + 255) & ~(size_t)255; };
  size_t zbt_b = align256((size_t)N_DIM * D_DIM * 2);
  size_t zft_b = align256((size_t)N_DIM * D_DIM * 4);
  size_t wb_b  = align256((size_t)M_DIM * D_DIM * 2);
  size_t ssq_b = align256((size_t)L_IT * C_CLS * N_DIM * 4);
  size_t out_b = align256((size_t)M_DIM * N_DIM * 2);

  if (zbt_b + zft_b + wb_b + ssq_b + out_b > ws_size) {
    hipMemsetAsync(d_out, 0, (size_t)D_DIM * N_DIM * 4, stream);
    return;
  }

  char* p = (char*)d_ws;
  bf16_t* ZbT  = (bf16_t*)p; p += zbt_b;
  float*  ZfT  = (float*)p;  p += zft_b;
  bf16_t* Wb   = (bf16_t*)p; p += wb_b;
  float*  ssq  = (float*)p;  p += ssq_b;
  bf16_t* OUT_T= (bf16_t*)p;

  hipMemsetAsync(ssq, 0, (size_t)L_IT * C_CLS * N_DIM * 4, stream);
  init_zt<<<dim3(N_DIM / 32, D_DIM / 32), 256, 0, stream>>>(Zin, ZfT, ZbT);

  for (int l = 0; l < L_IT; ++l) {
    const float* Cs = Cslist + (size_t)l * C_CLS * D_DIM * D_DIM;
    const float* El = Elist  + (size_t)l * D_DIM * D_DIM;
    float* ssq_l = ssq + (size_t)l * C_CLS * N_DIM;

    pack_w<<<dim3(M_DIM * D_DIM / 4 / 256), 256, 0, stream>>>(
        (const float4*)Cs, (const float4*)El, (bf16x4*)Wb);

    gemm_wz8<<<dim3(NBM * (N_DIM / 256)), 512, 0, stream>>>(
        Wb, ZbT, OUT_T, N_DIM, ssq_l);
    update2<<<dim3(N_DIM / 4), 256, 0, stream>>>(
        OUT_T, N_DIM, ssq_l, gamma, eta, temperature, ZfT, ZbT, 0);
  }
  final_out<<<dim3(N_DIM / 32, D_DIM / 32), 256, 0, stream>>>(ZfT, (float*)d_out);

  // ---- diagnostics (one dispatch each; write to dead ws regions) ----
  gemm_diag_full<<<dim3(256), 512, 0, stream>>>(Wb, ZbT, OUT_T, ssq);
  gemm_diag_nostage<<<dim3(256), 512, 0, stream>>>(Wb, ZbT, OUT_T, ssq);
}

// Round 12
// 1769.763 us; speedup vs baseline: 1.4756x; 1.4756x over previous
//
#include <hip/hip_runtime.h>
#include <hip/hip_bf16.h>
#include <stdint.h>

#define D_DIM 1024
#define N_DIM 4096
#define C_CLS 10
#define L_IT 8
#define M_DIM 11264   // (C+1)*D
#define NBM 44        // M_DIM / 256

typedef __bf16 bf16_t;
typedef __bf16 bf16x8 __attribute__((ext_vector_type(8)));
typedef __bf16 bf16x4 __attribute__((ext_vector_type(4)));
typedef float  f32x4  __attribute__((ext_vector_type(4)));
typedef unsigned short u16x8 __attribute__((ext_vector_type(8)));

__device__ __forceinline__ float bf2f(uint16_t u) {
  union { uint32_t i; float f; } x; x.i = ((uint32_t)u) << 16; return x.f;
}

// ---------------- pack W = [Cs ; E] fp32 -> bf16 ----------------
__global__ __launch_bounds__(256) void pack_w(const float4* __restrict__ Cs,
                                              const float4* __restrict__ El,
                                              bf16x4* __restrict__ dst) {
  const int CS4 = C_CLS * D_DIM * D_DIM / 4;
  int i = blockIdx.x * 256 + threadIdx.x;
  float4 v = (i < CS4) ? Cs[i] : El[i - CS4];
  bf16x4 o;
  o[0] = (bf16_t)v.x; o[1] = (bf16_t)v.y; o[2] = (bf16_t)v.z; o[3] = (bf16_t)v.w;
  dst[i] = o;
}

// ---------------- layer-0 init ----------------
__global__ __launch_bounds__(256) void init_zt(const float* __restrict__ Zin,
                                               float* __restrict__ ZfT,
                                               bf16_t* __restrict__ ZbT) {
  __shared__ float tile[32][33];
  int tx = threadIdx.x & 31, ty = threadIdx.x >> 5;
  int nb = blockIdx.x, db = blockIdx.y;
  int n = nb * 32 + tx;
#pragma unroll
  for (int j = 0; j < 32; j += 8) {
    int d = db * 32 + ty + j;
    tile[ty + j][tx] = Zin[(size_t)d * N_DIM + n];
  }
  __syncthreads();
  int d2 = db * 32 + tx;
#pragma unroll
  for (int j = 0; j < 32; j += 8) {
    int n2 = nb * 32 + ty + j;
    float v = tile[tx][ty + j];
    ZfT[(size_t)n2 * D_DIM + d2] = v;
    ZbT[(size_t)n2 * D_DIM + d2] = (bf16_t)v;
  }
}

// ---------------- final transpose-out ----------------
__global__ __launch_bounds__(256) void final_out(const float* __restrict__ ZfT,
                                                 float* __restrict__ outp) {
  __shared__ float tile[32][33];
  int tx = threadIdx.x & 31, ty = threadIdx.x >> 5;
  int nb = blockIdx.x, db = blockIdx.y;
#pragma unroll
  for (int j = 0; j < 32; j += 8) {
    int n = nb * 32 + ty + j;
    int d = db * 32 + tx;
    tile[ty + j][tx] = ZfT[(size_t)n * D_DIM + d];
  }
  __syncthreads();
#pragma unroll
  for (int j = 0; j < 32; j += 8) {
    int d2 = db * 32 + ty + j;
    int n2 = nb * 32 + tx;
    outp[(size_t)d2 * N_DIM + n2] = tile[tx][ty + j];
  }
}

// ================= 256x256 GEMM — m201 8-phase template, 16x16x32 MFMA =================
// OUT_T[col][row] = (Wb * ZbT^T)^T, stores NON-TEMPORAL (protect W/Z residency in L2/L3).
// 512 thr = 8 waves (2Mx4N), BK=64, K=1024 (16 K-tiles). vmcnt(6) at ph4/ph8 only.

#define SA(buf, h, t) do {                                                              \
    _Pragma("unroll") for (int e_ = 0; e_ < 2; ++e_) {                                  \
      const bf16_t* s_ = Wb + aoff0[e_] + (size_t)(h) * 65536 + (size_t)(t) * 64;       \
      __builtin_amdgcn_global_load_lds(                                                 \
        (const __attribute__((address_space(1))) void*)s_,                              \
        (__attribute__((address_space(3))) void*)(lds + (buf)*16384 + (h)*8192 + dstslot[e_]), \
        16, 0, 0);                                                                      \
    } } while (0)

#define SBst(buf, h, t) do {                                                            \
    _Pragma("unroll") for (int e_ = 0; e_ < 2; ++e_) {                                  \
      const bf16_t* s_ = ZbT + boff0[e_] + (size_t)(h) * 32768 + (size_t)(t) * 64;      \
      __builtin_amdgcn_global_load_lds(                                                 \
        (const __attribute__((address_space(1))) void*)s_,                              \
        (__attribute__((address_space(3))) void*)(lds + 32768 + (buf)*16384 + (h)*8192 + dstslot[e_]), \
        16, 0, 0);                                                                      \
    } } while (0)

#define LOAD_A(buf, qm) do {                                                            \
    _Pragma("unroll") for (int f_ = 0; f_ < 4; ++f_)                                    \
      _Pragma("unroll") for (int kk_ = 0; kk_ < 2; ++kk_)                               \
        a[f_][kk_] = *(const bf16x8*)(lds + (buf)*16384 + (qm)*8192 + aRowBase + f_*1024 + sidx[kk_]); \
  } while (0)

#define LOAD_Bq(buf, qn, arr) do {                                                      \
    _Pragma("unroll") for (int f_ = 0; f_ < 2; ++f_)                                    \
      _Pragma("unroll") for (int kk_ = 0; kk_ < 2; ++kk_)                               \
        arr[f_][kk_] = *(const bf16x8*)(lds + 32768 + (buf)*16384 + (qn)*8192 + bRowBase + f_*1024 + sidx[kk_]); \
  } while (0)

#define MFMAQ(qm, qn, arr) do {                                                         \
    _Pragma("unroll") for (int mm_ = 0; mm_ < 4; ++mm_)                                 \
      _Pragma("unroll") for (int nn_ = 0; nn_ < 2; ++nn_)                               \
        _Pragma("unroll") for (int kk_ = 0; kk_ < 2; ++kk_)                             \
          acc[(qm)*4+mm_][(qn)*2+nn_] = __builtin_amdgcn_mfma_f32_16x16x32_bf16(        \
            a[mm_][kk_], arr[nn_][kk_], acc[(qm)*4+mm_][(qn)*2+nn_], 0, 0, 0);          \
  } while (0)

#define BAR   __builtin_amdgcn_s_barrier()
#define VM(n) asm volatile("s_waitcnt vmcnt(" #n ")" ::: "memory")
#define LGKM8 asm volatile("s_waitcnt lgkmcnt(8)" ::: "memory")
#define PRIO1 __builtin_amdgcn_s_setprio(1)
#define PRIO0 __builtin_amdgcn_s_setprio(0)

#define PH8(qm, qn, arr, LOADS, STAGES, PREBAR, POSTMFMA) do {                          \
    LOADS;                                                                              \
    STAGES;                                                                             \
    PREBAR;                                                                             \
    BAR;                                                                                \
    asm volatile("s_waitcnt lgkmcnt(0)" ::: "memory");                                  \
    PRIO1;                                                                              \
    MFMAQ(qm, qn, arr);                                                                 \
    PRIO0;                                                                              \
    POSTMFMA;                                                                           \
    BAR;                                                                                \
  } while (0)

__global__ __launch_bounds__(512, 2) void gemm_wz8(const bf16_t* __restrict__ Wb,
                                                   const bf16_t* __restrict__ ZbT,
                                                   bf16_t* __restrict__ OUT_T, int ldn,
                                                   float* __restrict__ ssq) {
  __shared__ __align__(16) bf16_t lds[65536];  // 128 KiB

  // T1: bijective XCD swizzle (m204); nwg=704 -> q=88,r=0
  int nwg = gridDim.x;
  int bid = blockIdx.x;
  int q = nwg >> 3, r = nwg & 7;
  int xcd = bid & 7, idx = bid >> 3;
  int swz = (xcd < r ? xcd * (q + 1) : r * (q + 1) + (xcd - r) * q) + idx;
  int bm = swz % NBM, bn = swz / NBM;
  int m0 = bm * 256, n0 = bn * 256;

  int tid = threadIdx.x;
  int wave = tid >> 6, lane = tid & 63;
  int wrow = wave >> 2, wcol = wave & 3;
  int lm = lane & 15, lks = lane >> 4;
  int sw = lm & 7;

  size_t aoff0[2], boff0[2];
  int dstslot[2];
#pragma unroll
  for (int e = 0; e < 2; ++e) {
    int j = e * 512 + tid;
    int rih = j >> 3, sl = j & 7;
    int sg = sl ^ (rih & 7);                       // pre-swizzled global 16B slot
    int arow = (rih & 63) + ((rih >> 6) << 7);     // A halves: {0-63,128-191}/{+64}
    int brow = (rih & 31) + ((rih >> 5) << 6);     // B halves: 32-row interleave
    aoff0[e] = (size_t)(m0 + arow) * 1024 + sg * 8;
    boff0[e] = (size_t)(n0 + brow) * 1024 + sg * 8;
    dstslot[e] = e * 4096 + wave * 512;
  }

  int aRowBase = (wrow * 64 + lm) * 64;
  int bRowBase = (wcol * 32 + lm) * 64;
  int sidx[2] = { ((0 + lks) ^ sw) * 8, ((4 + lks) ^ sw) * 8 };

  f32x4 acc[8][4] = {};
  bf16x8 a[4][2], b0[2][2], b1[2][2];

  // prologue: E0.{A0,B0,B1,A1} + O0.{A0,B0,B1}; vmcnt(6) completes E0.
  SA(0, 0, 0); SBst(0, 0, 0); SBst(0, 1, 0); SA(0, 1, 0);
  SA(1, 0, 1); SBst(1, 0, 1); SBst(1, 1, 1);
  VM(6);
  BAR;

  for (int it = 0; it < 8; ++it) {
    int tO = 2 * it + 1, tN = 2 * it + 2, tM = 2 * it + 3;
    bool st = (it < 7);

    // p1: E qm0 qn0 (12 reads); stage O.A1
    PH8(0, 0, b0, LOAD_A(0, 0); LOAD_Bq(0, 0, b0), SA(1, 1, tO), LGKM8, );
    // p2: E qm0 qn1 (4 reads); stage N.A0
    PH8(0, 1, b1, LOAD_Bq(0, 1, b1), { if (st) SA(0, 0, tN); }, , );
    // p3: E qm1 qn0 (8 reads); stage N.B0
    PH8(1, 0, b0, LOAD_A(0, 1), { if (st) SBst(0, 0, tN); }, , );
    // p4: E qm1 qn1 (0 reads); stage N.B1; vmcnt
    PH8(1, 1, b1, , { if (st) SBst(0, 1, tN); }, ,
        { if (st) { VM(6); } else { VM(0); } });
    // p5: O qm0 qn0 (12 reads); stage N.A1
    PH8(0, 0, b0, LOAD_A(1, 0); LOAD_Bq(1, 0, b0), { if (st) SA(0, 1, tN); }, LGKM8, );
    // p6: O qm0 qn1 (4 reads); stage M.A0
    PH8(0, 1, b1, LOAD_Bq(1, 1, b1), { if (st) SA(1, 0, tM); }, , );
    // p7: O qm1 qn0 (8 reads); stage M.B0
    PH8(1, 0, b0, LOAD_A(1, 1), { if (st) SBst(1, 0, tM); }, , );
    // p8: O qm1 qn1 (0 reads); stage M.B1; vmcnt
    PH8(1, 1, b1, , { if (st) SBst(1, 1, tM); }, , { if (st) VM(6); });
  }

  // C-write (transposed, NON-TEMPORAL): OUT_T[col][row]; 4 acc rows contiguous
#pragma unroll
  for (int mf = 0; mf < 8; ++mf)
#pragma unroll
    for (int nf = 0; nf < 4; ++nf) {
      int col = n0 + wcol * 64 + nf * 16 + lm;
      int row = m0 + wrow * 128 + mf * 16 + lks * 4;
      bf16x4 v;
#pragma unroll
      for (int rr = 0; rr < 4; ++rr) v[rr] = (bf16_t)acc[mf][nf][rr];
      __builtin_nontemporal_store(v, (bf16x4*)(OUT_T + (size_t)col * M_DIM + row));
    }

  // fused per-class column sum-of-squares (class blocks only; E rows skip)
  if (m0 < C_CLS * 1024) {
    int c = m0 >> 10;
#pragma unroll
    for (int nf = 0; nf < 4; ++nf) {
      float v = 0.f;
#pragma unroll
      for (int mf = 0; mf < 8; ++mf)
#pragma unroll
        for (int rr = 0; rr < 4; ++rr)
          v += acc[mf][nf][rr] * acc[mf][nf][rr];
      v += __shfl_xor(v, 16);
      v += __shfl_xor(v, 32);
      if (lks == 0)
        atomicAdd(&ssq[(size_t)c * ldn + n0 + wcol * 64 + nf * 16 + lm], v);
    }
  }
}

// ---------------- fused softmax + update + normalize + ZbT emit ----------------
// OUT_T / ZfT accesses non-temporal (single-use streams); ZbT normal (GEMM B operand).
__global__ __launch_bounds__(256) void update2(const bf16_t* __restrict__ OUT_T, int Nc,
                                               const float* __restrict__ ssq,
                                               const float* __restrict__ gamma,
                                               const float* __restrict__ etap,
                                               const float* __restrict__ tempr,
                                               float* __restrict__ ZfT,
                                               bf16_t* __restrict__ ZbT,
                                               int n_off) {
  int wv = threadIdx.x >> 6, lane = threadIdx.x & 63;
  int nl = blockIdx.x * 4 + wv;
  if (nl >= Nc) return;
  int n = n_off + nl;
  float eta = etap[0], invT = 1.0f / tempr[0];

  float s[C_CLS], m = -1e30f;
#pragma unroll
  for (int c = 0; c < C_CLS; ++c) {
    float sim = -sqrtf(ssq[(size_t)c * Nc + nl]);
    s[c] = sim;
    m = fmaxf(m, sim);
  }
  float sum = 0.f;
#pragma unroll
  for (int c = 0; c < C_CLS; ++c) {
    float e = __expf((s[c] - m) * invT);
    s[c] = e;
    sum += e;
  }
  float invsum = 1.0f / sum;
  float gP[C_CLS];
#pragma unroll
  for (int c = 0; c < C_CLS; ++c) gP[c] = gamma[c] * s[c] * invsum;

  const u16x8* ob = (const u16x8*)(OUT_T + (size_t)nl * M_DIM) + lane * 2;
  float term[16] = {};
#pragma unroll
  for (int c = 0; c < C_CLS; ++c) {
    u16x8 v0 = __builtin_nontemporal_load(ob + c * 128);
    u16x8 v1 = __builtin_nontemporal_load(ob + c * 128 + 1);
#pragma unroll
    for (int j = 0; j < 8; ++j) {
      term[j]     += gP[c] * bf2f(v0[j]);
      term[8 + j] += gP[c] * bf2f(v1[j]);
    }
  }
  u16x8 g0 = __builtin_nontemporal_load(ob + C_CLS * 128);
  u16x8 g1 = __builtin_nontemporal_load(ob + C_CLS * 128 + 1);

  const f32x4* zp = (const f32x4*)(ZfT + (size_t)n * D_DIM) + lane * 4;
  f32x4 z[4];
#pragma unroll
  for (int q4 = 0; q4 < 4; ++q4) z[q4] = __builtin_nontemporal_load(zp + q4);

  float zn[16];
  float ss = 0.f;
#pragma unroll
  for (int j = 0; j < 16; ++j) {
    float g = bf2f(j < 8 ? g0[j & 7] : g1[j & 7]);
    float v = z[j >> 2][j & 3] + eta * (g - term[j]);
    zn[j] = v;
    ss += v * v;
  }
#pragma unroll
  for (int k = 1; k < 64; k <<= 1) ss += __shfl_xor(ss, k);
  float inv = rsqrtf(ss);

  f32x4* zo = (f32x4*)(ZfT + (size_t)n * D_DIM) + lane * 4;
  bf16x8* bo = (bf16x8*)(ZbT + (size_t)n * D_DIM) + lane * 2;
#pragma unroll
  for (int q4 = 0; q4 < 4; ++q4) {
    f32x4 o;
#pragma unroll
    for (int j = 0; j < 4; ++j) o[j] = zn[q4 * 4 + j] * inv;
    __builtin_nontemporal_store(o, zo + q4);
  }
#pragma unroll
  for (int h = 0; h < 2; ++h) {
    bf16x8 o;
#pragma unroll
    for (int j = 0; j < 8; ++j) o[j] = (bf16_t)(zn[h * 8 + j] * inv);
    bo[h] = o;   // ZbT: keep cache-resident (GEMM B operand next layer)
  }
}

extern "C" void kernel_launch(void* const* d_in, const int* in_sizes, int n_in,
                              void* d_out, int out_size, void* d_ws, size_t ws_size,
                              hipStream_t stream) {
  (void)in_sizes; (void)n_in; (void)out_size;
  const float* Zin        = (const float*)d_in[0];
  const float* Elist      = (const float*)d_in[1];
  const float* Cslist     = (const float*)d_in[2];
  const float* gamma      = (const float*)d_in[3];
  const float* eta        = (const float*)d_in[4];
  const float* temperature= (const float*)d_in[5];

  auto align256 = [](size_t x) { return (x + 255) & ~(size_t)255; };
  size_t zbt_b = align256((size_t)N_DIM * D_DIM * 2);
  size_t zft_b = align256((size_t)N_DIM * D_DIM * 4);
  size_t wb_b  = align256((size_t)M_DIM * D_DIM * 2);
  size_t ssq_b = align256((size_t)L_IT * C_CLS * N_DIM * 4);
  size_t out_b = align256((size_t)M_DIM * N_DIM * 2);

  if (zbt_b + zft_b + wb_b + ssq_b + out_b > ws_size) {
    hipMemsetAsync(d_out, 0, (size_t)D_DIM * N_DIM * 4, stream);
    return;
  }

  char* p = (char*)d_ws;
  bf16_t* ZbT  = (bf16_t*)p; p += zbt_b;
  float*  ZfT  = (float*)p;  p += zft_b;
  bf16_t* Wb   = (bf16_t*)p; p += wb_b;
  float*  ssq  = (float*)p;  p += ssq_b;
  bf16_t* OUT_T= (bf16_t*)p;

  hipMemsetAsync(ssq, 0, (size_t)L_IT * C_CLS * N_DIM * 4, stream);
  init_zt<<<dim3(N_DIM / 32, D_DIM / 32), 256, 0, stream>>>(Zin, ZfT, ZbT);

  for (int l = 0; l < L_IT; ++l) {
    const float* Cs = Cslist + (size_t)l * C_CLS * D_DIM * D_DIM;
    const float* El = Elist  + (size_t)l * D_DIM * D_DIM;
    float* ssq_l = ssq + (size_t)l * C_CLS * N_DIM;

    pack_w<<<dim3(M_DIM * D_DIM / 4 / 256), 256, 0, stream>>>(
        (const float4*)Cs, (const float4*)El, (bf16x4*)Wb);

    gemm_wz8<<<dim3(NBM * (N_DIM / 256)), 512, 0, stream>>>(
        Wb, ZbT, OUT_T, N_DIM, ssq_l);
    update2<<<dim3(N_DIM / 4), 256, 0, stream>>>(
        OUT_T, N_DIM, ssq_l, gamma, eta, temperature, ZfT, ZbT, 0);
  }
  final_out<<<dim3(N_DIM / 32, D_DIM / 32), 256, 0, stream>>>(ZfT, (float*)d_out);
}

// Round 13
// 1221.478 us; speedup vs baseline: 2.1380x; 1.4489x over previous
//
#include <hip/hip_runtime.h>
#include <hip/hip_bf16.h>
#include <stdint.h>

#define D_DIM 1024
#define N_DIM 4096
#define C_CLS 10
#define L_IT 8
#define M_DIM 11264   // (C+1)*D
#define NBM 44        // M_DIM / 256

typedef __bf16 bf16_t;
typedef __bf16 bf16x8 __attribute__((ext_vector_type(8)));
typedef __bf16 bf16x4 __attribute__((ext_vector_type(4)));
typedef float  f32x4  __attribute__((ext_vector_type(4)));
typedef unsigned short u16x8 __attribute__((ext_vector_type(8)));

__device__ __forceinline__ float bf2f(uint16_t u) {
  union { uint32_t i; float f; } x; x.i = ((uint32_t)u) << 16; return x.f;
}

// ---------------- pack W = [Cs ; E] fp32 -> bf16 ----------------
__global__ __launch_bounds__(256) void pack_w(const float4* __restrict__ Cs,
                                              const float4* __restrict__ El,
                                              bf16x4* __restrict__ dst) {
  const int CS4 = C_CLS * D_DIM * D_DIM / 4;
  int i = blockIdx.x * 256 + threadIdx.x;
  float4 v = (i < CS4) ? Cs[i] : El[i - CS4];
  bf16x4 o;
  o[0] = (bf16_t)v.x; o[1] = (bf16_t)v.y; o[2] = (bf16_t)v.z; o[3] = (bf16_t)v.w;
  dst[i] = o;
}

// ---------------- layer-0 init ----------------
__global__ __launch_bounds__(256) void init_zt(const float* __restrict__ Zin,
                                               float* __restrict__ ZfT,
                                               bf16_t* __restrict__ ZbT) {
  __shared__ float tile[32][33];
  int tx = threadIdx.x & 31, ty = threadIdx.x >> 5;
  int nb = blockIdx.x, db = blockIdx.y;
  int n = nb * 32 + tx;
#pragma unroll
  for (int j = 0; j < 32; j += 8) {
    int d = db * 32 + ty + j;
    tile[ty + j][tx] = Zin[(size_t)d * N_DIM + n];
  }
  __syncthreads();
  int d2 = db * 32 + tx;
#pragma unroll
  for (int j = 0; j < 32; j += 8) {
    int n2 = nb * 32 + ty + j;
    float v = tile[tx][ty + j];
    ZfT[(size_t)n2 * D_DIM + d2] = v;
    ZbT[(size_t)n2 * D_DIM + d2] = (bf16_t)v;
  }
}

// ---------------- final transpose-out ----------------
__global__ __launch_bounds__(256) void final_out(const float* __restrict__ ZfT,
                                                 float* __restrict__ outp) {
  __shared__ float tile[32][33];
  int tx = threadIdx.x & 31, ty = threadIdx.x >> 5;
  int nb = blockIdx.x, db = blockIdx.y;
#pragma unroll
  for (int j = 0; j < 32; j += 8) {
    int n = nb * 32 + ty + j;
    int d = db * 32 + tx;
    tile[ty + j][tx] = ZfT[(size_t)n * D_DIM + d];
  }
  __syncthreads();
#pragma unroll
  for (int j = 0; j < 32; j += 8) {
    int d2 = db * 32 + ty + j;
    int n2 = nb * 32 + tx;
    outp[(size_t)d2 * N_DIM + n2] = tile[tx][ty + j];
  }
}

// ================= 256x256 GEMM — m201 8-phase template, 16x16x32 MFMA =================
// OUT_T[col][row] = (Wb * ZbT^T)^T. 512 thr = 8 waves (2Mx4N), BK=64, K=1024 (16 K-tiles).
// Tile mapping: bn-FASTEST within each XCD chunk (bm = swz/16, bn = swz%16) so the
// ~32 co-resident blocks per XCD share 2 A-panels (1 MB, L2-hot, 16x reuse each)
// while B panels stream L3->L2. (r13: fixes the L2 thrash that made staging
// latency-bound — diag r11: staging = 78% of K-loop at 30 B/cy/CU feed.)

#define SA(buf, h, t) do {                                                              \
    _Pragma("unroll") for (int e_ = 0; e_ < 2; ++e_) {                                  \
      const bf16_t* s_ = Wb + aoff0[e_] + (size_t)(h) * 65536 + (size_t)(t) * 64;       \
      __builtin_amdgcn_global_load_lds(                                                 \
        (const __attribute__((address_space(1))) void*)s_,                              \
        (__attribute__((address_space(3))) void*)(lds + (buf)*16384 + (h)*8192 + dstslot[e_]), \
        16, 0, 0);                                                                      \
    } } while (0)

#define SBst(buf, h, t) do {                                                            \
    _Pragma("unroll") for (int e_ = 0; e_ < 2; ++e_) {                                  \
      const bf16_t* s_ = ZbT + boff0[e_] + (size_t)(h) * 32768 + (size_t)(t) * 64;      \
      __builtin_amdgcn_global_load_lds(                                                 \
        (const __attribute__((address_space(1))) void*)s_,                              \
        (__attribute__((address_space(3))) void*)(lds + 32768 + (buf)*16384 + (h)*8192 + dstslot[e_]), \
        16, 0, 0);                                                                      \
    } } while (0)

#define LOAD_A(buf, qm) do {                                                            \
    _Pragma("unroll") for (int f_ = 0; f_ < 4; ++f_)                                    \
      _Pragma("unroll") for (int kk_ = 0; kk_ < 2; ++kk_)                               \
        a[f_][kk_] = *(const bf16x8*)(lds + (buf)*16384 + (qm)*8192 + aRowBase + f_*1024 + sidx[kk_]); \
  } while (0)

#define LOAD_Bq(buf, qn, arr) do {                                                      \
    _Pragma("unroll") for (int f_ = 0; f_ < 2; ++f_)                                    \
      _Pragma("unroll") for (int kk_ = 0; kk_ < 2; ++kk_)                               \
        arr[f_][kk_] = *(const bf16x8*)(lds + 32768 + (buf)*16384 + (qn)*8192 + bRowBase + f_*1024 + sidx[kk_]); \
  } while (0)

#define MFMAQ(qm, qn, arr) do {                                                         \
    _Pragma("unroll") for (int mm_ = 0; mm_ < 4; ++mm_)                                 \
      _Pragma("unroll") for (int nn_ = 0; nn_ < 2; ++nn_)                               \
        _Pragma("unroll") for (int kk_ = 0; kk_ < 2; ++kk_)                             \
          acc[(qm)*4+mm_][(qn)*2+nn_] = __builtin_amdgcn_mfma_f32_16x16x32_bf16(        \
            a[mm_][kk_], arr[nn_][kk_], acc[(qm)*4+mm_][(qn)*2+nn_], 0, 0, 0);          \
  } while (0)

#define BAR   __builtin_amdgcn_s_barrier()
#define VM(n) asm volatile("s_waitcnt vmcnt(" #n ")" ::: "memory")
#define LGKM8 asm volatile("s_waitcnt lgkmcnt(8)" ::: "memory")
#define PRIO1 __builtin_amdgcn_s_setprio(1)
#define PRIO0 __builtin_amdgcn_s_setprio(0)

#define PH8(qm, qn, arr, LOADS, STAGES, PREBAR, POSTMFMA) do {                          \
    LOADS;                                                                              \
    STAGES;                                                                             \
    PREBAR;                                                                             \
    BAR;                                                                                \
    asm volatile("s_waitcnt lgkmcnt(0)" ::: "memory");                                  \
    PRIO1;                                                                              \
    MFMAQ(qm, qn, arr);                                                                 \
    PRIO0;                                                                              \
    POSTMFMA;                                                                           \
    BAR;                                                                                \
  } while (0)

__global__ __launch_bounds__(512, 2) void gemm_wz8(const bf16_t* __restrict__ Wb,
                                                   const bf16_t* __restrict__ ZbT,
                                                   bf16_t* __restrict__ OUT_T, int ldn,
                                                   float* __restrict__ ssq) {
  __shared__ __align__(16) bf16_t lds[65536];  // 128 KiB

  // T1: bijective XCD swizzle (m204); nwg=704 -> q=88,r=0
  int nwg = gridDim.x;
  int bid = blockIdx.x;
  int q = nwg >> 3, r = nwg & 7;
  int xcd = bid & 7, idx = bid >> 3;
  int swz = (xcd < r ? xcd * (q + 1) : r * (q + 1) + (xcd - r) * q) + idx;
  // bn-FASTEST within chunk: co-resident blocks share A panels (L2-hot)
  int bm = swz >> 4, bn = swz & 15;
  int m0 = bm * 256, n0 = bn * 256;

  int tid = threadIdx.x;
  int wave = tid >> 6, lane = tid & 63;
  int wrow = wave >> 2, wcol = wave & 3;
  int lm = lane & 15, lks = lane >> 4;
  int sw = lm & 7;

  size_t aoff0[2], boff0[2];
  int dstslot[2];
#pragma unroll
  for (int e = 0; e < 2; ++e) {
    int j = e * 512 + tid;
    int rih = j >> 3, sl = j & 7;
    int sg = sl ^ (rih & 7);                       // pre-swizzled global 16B slot
    int arow = (rih & 63) + ((rih >> 6) << 7);     // A halves: {0-63,128-191}/{+64}
    int brow = (rih & 31) + ((rih >> 5) << 6);     // B halves: 32-row interleave
    aoff0[e] = (size_t)(m0 + arow) * 1024 + sg * 8;
    boff0[e] = (size_t)(n0 + brow) * 1024 + sg * 8;
    dstslot[e] = e * 4096 + wave * 512;
  }

  int aRowBase = (wrow * 64 + lm) * 64;
  int bRowBase = (wcol * 32 + lm) * 64;
  int sidx[2] = { ((0 + lks) ^ sw) * 8, ((4 + lks) ^ sw) * 8 };

  f32x4 acc[8][4] = {};
  bf16x8 a[4][2], b0[2][2], b1[2][2];

  // prologue: E0.{A0,B0,B1,A1} + O0.{A0,B0,B1}; vmcnt(6) completes E0.
  SA(0, 0, 0); SBst(0, 0, 0); SBst(0, 1, 0); SA(0, 1, 0);
  SA(1, 0, 1); SBst(1, 0, 1); SBst(1, 1, 1);
  VM(6);
  BAR;

  for (int it = 0; it < 8; ++it) {
    int tO = 2 * it + 1, tN = 2 * it + 2, tM = 2 * it + 3;
    bool st = (it < 7);

    // p1: E qm0 qn0 (12 reads); stage O.A1
    PH8(0, 0, b0, LOAD_A(0, 0); LOAD_Bq(0, 0, b0), SA(1, 1, tO), LGKM8, );
    // p2: E qm0 qn1 (4 reads); stage N.A0
    PH8(0, 1, b1, LOAD_Bq(0, 1, b1), { if (st) SA(0, 0, tN); }, , );
    // p3: E qm1 qn0 (8 reads); stage N.B0
    PH8(1, 0, b0, LOAD_A(0, 1), { if (st) SBst(0, 0, tN); }, , );
    // p4: E qm1 qn1 (0 reads); stage N.B1; vmcnt
    PH8(1, 1, b1, , { if (st) SBst(0, 1, tN); }, ,
        { if (st) { VM(6); } else { VM(0); } });
    // p5: O qm0 qn0 (12 reads); stage N.A1
    PH8(0, 0, b0, LOAD_A(1, 0); LOAD_Bq(1, 0, b0), { if (st) SA(0, 1, tN); }, LGKM8, );
    // p6: O qm0 qn1 (4 reads); stage M.A0
    PH8(0, 1, b1, LOAD_Bq(1, 1, b1), { if (st) SA(1, 0, tM); }, , );
    // p7: O qm1 qn0 (8 reads); stage M.B0
    PH8(1, 0, b0, LOAD_A(1, 1), { if (st) SBst(1, 0, tM); }, , );
    // p8: O qm1 qn1 (0 reads); stage M.B1; vmcnt
    PH8(1, 1, b1, , { if (st) SBst(1, 1, tM); }, , { if (st) VM(6); });
  }

  // C-write (transposed): OUT_T[col][row]; 4 acc rows contiguous -> 8B store
#pragma unroll
  for (int mf = 0; mf < 8; ++mf)
#pragma unroll
    for (int nf = 0; nf < 4; ++nf) {
      int col = n0 + wcol * 64 + nf * 16 + lm;
      int row = m0 + wrow * 128 + mf * 16 + lks * 4;
      bf16x4 v;
#pragma unroll
      for (int rr = 0; rr < 4; ++rr) v[rr] = (bf16_t)acc[mf][nf][rr];
      *(bf16x4*)(OUT_T + (size_t)col * M_DIM + row) = v;
    }

  // fused per-class column sum-of-squares (class blocks only; E rows skip)
  if (m0 < C_CLS * 1024) {
    int c = m0 >> 10;
#pragma unroll
    for (int nf = 0; nf < 4; ++nf) {
      float v = 0.f;
#pragma unroll
      for (int mf = 0; mf < 8; ++mf)
#pragma unroll
        for (int rr = 0; rr < 4; ++rr)
          v += acc[mf][nf][rr] * acc[mf][nf][rr];
      v += __shfl_xor(v, 16);
      v += __shfl_xor(v, 32);
      if (lks == 0)
        atomicAdd(&ssq[(size_t)c * ldn + n0 + wcol * 64 + nf * 16 + lm], v);
    }
  }
}

// ---------------- fused softmax + update + normalize + ZbT emit ----------------
__global__ __launch_bounds__(256) void update2(const bf16_t* __restrict__ OUT_T, int Nc,
                                               const float* __restrict__ ssq,
                                               const float* __restrict__ gamma,
                                               const float* __restrict__ etap,
                                               const float* __restrict__ tempr,
                                               float* __restrict__ ZfT,
                                               bf16_t* __restrict__ ZbT,
                                               int n_off) {
  int wv = threadIdx.x >> 6, lane = threadIdx.x & 63;
  int nl = blockIdx.x * 4 + wv;
  if (nl >= Nc) return;
  int n = n_off + nl;
  float eta = etap[0], invT = 1.0f / tempr[0];

  float s[C_CLS], m = -1e30f;
#pragma unroll
  for (int c = 0; c < C_CLS; ++c) {
    float sim = -sqrtf(ssq[(size_t)c * Nc + nl]);
    s[c] = sim;
    m = fmaxf(m, sim);
  }
  float sum = 0.f;
#pragma unroll
  for (int c = 0; c < C_CLS; ++c) {
    float e = __expf((s[c] - m) * invT);
    s[c] = e;
    sum += e;
  }
  float invsum = 1.0f / sum;
  float gP[C_CLS];
#pragma unroll
  for (int c = 0; c < C_CLS; ++c) gP[c] = gamma[c] * s[c] * invsum;

  const u16x8* ob = (const u16x8*)(OUT_T + (size_t)nl * M_DIM) + lane * 2;
  float term[16] = {};
#pragma unroll
  for (int c = 0; c < C_CLS; ++c) {
    u16x8 v0 = ob[c * 128], v1 = ob[c * 128 + 1];
#pragma unroll
    for (int j = 0; j < 8; ++j) {
      term[j]     += gP[c] * bf2f(v0[j]);
      term[8 + j] += gP[c] * bf2f(v1[j]);
    }
  }
  u16x8 g0 = ob[C_CLS * 128], g1 = ob[C_CLS * 128 + 1];

  const f32x4* zp = (const f32x4*)(ZfT + (size_t)n * D_DIM) + lane * 4;
  f32x4 z[4] = { zp[0], zp[1], zp[2], zp[3] };

  float zn[16];
  float ss = 0.f;
#pragma unroll
  for (int j = 0; j < 16; ++j) {
    float g = bf2f(j < 8 ? g0[j & 7] : g1[j & 7]);
    float v = z[j >> 2][j & 3] + eta * (g - term[j]);
    zn[j] = v;
    ss += v * v;
  }
#pragma unroll
  for (int k = 1; k < 64; k <<= 1) ss += __shfl_xor(ss, k);
  float inv = rsqrtf(ss);

  f32x4* zo = (f32x4*)(ZfT + (size_t)n * D_DIM) + lane * 4;
  bf16x8* bo = (bf16x8*)(ZbT + (size_t)n * D_DIM) + lane * 2;
#pragma unroll
  for (int q4 = 0; q4 < 4; ++q4) {
    f32x4 o;
#pragma unroll
    for (int j = 0; j < 4; ++j) o[j] = zn[q4 * 4 + j] * inv;
    zo[q4] = o;
  }
#pragma unroll
  for (int h = 0; h < 2; ++h) {
    bf16x8 o;
#pragma unroll
    for (int j = 0; j < 8; ++j) o[j] = (bf16_t)(zn[h * 8 + j] * inv);
    bo[h] = o;
  }
}

extern "C" void kernel_launch(void* const* d_in, const int* in_sizes, int n_in,
                              void* d_out, int out_size, void* d_ws, size_t ws_size,
                              hipStream_t stream) {
  (void)in_sizes; (void)n_in; (void)out_size;
  const float* Zin        = (const float*)d_in[0];
  const float* Elist      = (const float*)d_in[1];
  const float* Cslist     = (const float*)d_in[2];
  const float* gamma      = (const float*)d_in[3];
  const float* eta        = (const float*)d_in[4];
  const float* temperature= (const float*)d_in[5];

  auto align256 = [](size_t x) { return (x + 255) & ~(size_t)255; };
  size_t zbt_b = align256((size_t)N_DIM * D_DIM * 2);
  size_t zft_b = align256((size_t)N_DIM * D_DIM * 4);
  size_t wb_b  = align256((size_t)M_DIM * D_DIM * 2);
  size_t ssq_b = align256((size_t)L_IT * C_CLS * N_DIM * 4);
  size_t out_b = align256((size_t)M_DIM * N_DIM * 2);

  if (zbt_b + zft_b + wb_b + ssq_b + out_b > ws_size) {
    hipMemsetAsync(d_out, 0, (size_t)D_DIM * N_DIM * 4, stream);
    return;
  }

  char* p = (char*)d_ws;
  bf16_t* ZbT  = (bf16_t*)p; p += zbt_b;
  float*  ZfT  = (float*)p;  p += zft_b;
  bf16_t* Wb   = (bf16_t*)p; p += wb_b;
  float*  ssq  = (float*)p;  p += ssq_b;
  bf16_t* OUT_T= (bf16_t*)p;

  hipMemsetAsync(ssq, 0, (size_t)L_IT * C_CLS * N_DIM * 4, stream);
  init_zt<<<dim3(N_DIM / 32, D_DIM / 32), 256, 0, stream>>>(Zin, ZfT, ZbT);

  for (int l = 0; l < L_IT; ++l) {
    const float* Cs = Cslist + (size_t)l * C_CLS * D_DIM * D_DIM;
    const float* El = Elist  + (size_t)l * D_DIM * D_DIM;
    float* ssq_l = ssq + (size_t)l * C_CLS * N_DIM;

    pack_w<<<dim3(M_DIM * D_DIM / 4 / 256), 256, 0, stream>>>(
        (const float4*)Cs, (const float4*)El, (bf16x4*)Wb);

    gemm_wz8<<<dim3(NBM * (N_DIM / 256)), 512, 0, stream>>>(
        Wb, ZbT, OUT_T, N_DIM, ssq_l);
    update2<<<dim3(N_DIM / 4), 256, 0, stream>>>(
        OUT_T, N_DIM, ssq_l, gamma, eta, temperature, ZfT, ZbT, 0);
  }
  final_out<<<dim3(N_DIM / 32, D_DIM / 32), 256, 0, stream>>>(ZfT, (float*)d_out);
}

// Round 14
// 1201.015 us; speedup vs baseline: 2.1744x; 1.0170x over previous
//
#include <hip/hip_runtime.h>
#include <hip/hip_bf16.h>
#include <stdint.h>

#define D_DIM 1024
#define N_DIM 4096
#define C_CLS 10
#define L_IT 8
#define M_DIM 11264   // (C+1)*D
#define NBM 44        // M_DIM / 256
#define PACK_BLOCKS 11264   // M_DIM*D_DIM/4/256
#define UPD_BLOCKS 1024     // N_DIM/4

typedef __bf16 bf16_t;
typedef __bf16 bf16x8 __attribute__((ext_vector_type(8)));
typedef __bf16 bf16x4 __attribute__((ext_vector_type(4)));
typedef float  f32x4  __attribute__((ext_vector_type(4)));
typedef unsigned short u16x8 __attribute__((ext_vector_type(8)));

__device__ __forceinline__ float bf2f(uint16_t u) {
  union { uint32_t i; float f; } x; x.i = ((uint32_t)u) << 16; return x.f;
}

__device__ __forceinline__ void pack_body(const float4* __restrict__ Cs,
                                          const float4* __restrict__ El,
                                          bf16x4* __restrict__ dst, int i) {
  const int CS4 = C_CLS * D_DIM * D_DIM / 4;
  float4 v = (i < CS4) ? Cs[i] : El[i - CS4];
  bf16x4 o;
  o[0] = (bf16_t)v.x; o[1] = (bf16_t)v.y; o[2] = (bf16_t)v.z; o[3] = (bf16_t)v.w;
  dst[i] = o;
}

// ---------------- fat kernel: layer-0 init (+ pack layer-0 W) ----------------
__global__ __launch_bounds__(256) void init_pack(const float* __restrict__ Zin,
                                                 float* __restrict__ ZfT,
                                                 bf16_t* __restrict__ ZbT,
                                                 const float4* __restrict__ Cs0,
                                                 const float4* __restrict__ El0,
                                                 bf16x4* __restrict__ Wb0) {
  if (blockIdx.x < PACK_BLOCKS) {
    pack_body(Cs0, El0, Wb0, blockIdx.x * 256 + threadIdx.x);
    return;
  }
  int idx = blockIdx.x - PACK_BLOCKS;          // 4096 init blocks
  int nb = idx & 127, db = idx >> 7;           // N/32=128, D/32=32
  __shared__ float tile[32][33];
  int tx = threadIdx.x & 31, ty = threadIdx.x >> 5;
  int n = nb * 32 + tx;
#pragma unroll
  for (int j = 0; j < 32; j += 8) {
    int d = db * 32 + ty + j;
    tile[ty + j][tx] = Zin[(size_t)d * N_DIM + n];
  }
  __syncthreads();
  int d2 = db * 32 + tx;
#pragma unroll
  for (int j = 0; j < 32; j += 8) {
    int n2 = nb * 32 + ty + j;
    float v = tile[tx][ty + j];
    ZfT[(size_t)n2 * D_DIM + d2] = v;
    ZbT[(size_t)n2 * D_DIM + d2] = (bf16_t)v;
  }
}

// ---------------- final transpose-out ----------------
__global__ __launch_bounds__(256) void final_out(const float* __restrict__ ZfT,
                                                 float* __restrict__ outp) {
  __shared__ float tile[32][33];
  int tx = threadIdx.x & 31, ty = threadIdx.x >> 5;
  int nb = blockIdx.x, db = blockIdx.y;
#pragma unroll
  for (int j = 0; j < 32; j += 8) {
    int n = nb * 32 + ty + j;
    int d = db * 32 + tx;
    tile[ty + j][tx] = ZfT[(size_t)n * D_DIM + d];
  }
  __syncthreads();
#pragma unroll
  for (int j = 0; j < 32; j += 8) {
    int d2 = db * 32 + ty + j;
    int n2 = nb * 32 + tx;
    outp[(size_t)d2 * N_DIM + n2] = tile[tx][ty + j];
  }
}

// ================= 256x256 GEMM — m201 8-phase template, 16x16x32 MFMA =================
// (unchanged from r13: bn-fastest XCD mapping, vmcnt(6)@ph4/ph8, lgkm(8) discipline)

#define SA(buf, h, t) do {                                                              \
    _Pragma("unroll") for (int e_ = 0; e_ < 2; ++e_) {                                  \
      const bf16_t* s_ = Wb + aoff0[e_] + (size_t)(h) * 65536 + (size_t)(t) * 64;       \
      __builtin_amdgcn_global_load_lds(                                                 \
        (const __attribute__((address_space(1))) void*)s_,                              \
        (__attribute__((address_space(3))) void*)(lds + (buf)*16384 + (h)*8192 + dstslot[e_]), \
        16, 0, 0);                                                                      \
    } } while (0)

#define SBst(buf, h, t) do {                                                            \
    _Pragma("unroll") for (int e_ = 0; e_ < 2; ++e_) {                                  \
      const bf16_t* s_ = ZbT + boff0[e_] + (size_t)(h) * 32768 + (size_t)(t) * 64;      \
      __builtin_amdgcn_global_load_lds(                                                 \
        (const __attribute__((address_space(1))) void*)s_,                              \
        (__attribute__((address_space(3))) void*)(lds + 32768 + (buf)*16384 + (h)*8192 + dstslot[e_]), \
        16, 0, 0);                                                                      \
    } } while (0)

#define LOAD_A(buf, qm) do {                                                            \
    _Pragma("unroll") for (int f_ = 0; f_ < 4; ++f_)                                    \
      _Pragma("unroll") for (int kk_ = 0; kk_ < 2; ++kk_)                               \
        a[f_][kk_] = *(const bf16x8*)(lds + (buf)*16384 + (qm)*8192 + aRowBase + f_*1024 + sidx[kk_]); \
  } while (0)

#define LOAD_Bq(buf, qn, arr) do {                                                      \
    _Pragma("unroll") for (int f_ = 0; f_ < 2; ++f_)                                    \
      _Pragma("unroll") for (int kk_ = 0; kk_ < 2; ++kk_)                               \
        arr[f_][kk_] = *(const bf16x8*)(lds + 32768 + (buf)*16384 + (qn)*8192 + bRowBase + f_*1024 + sidx[kk_]); \
  } while (0)

#define MFMAQ(qm, qn, arr) do {                                                         \
    _Pragma("unroll") for (int mm_ = 0; mm_ < 4; ++mm_)                                 \
      _Pragma("unroll") for (int nn_ = 0; nn_ < 2; ++nn_)                               \
        _Pragma("unroll") for (int kk_ = 0; kk_ < 2; ++kk_)                             \
          acc[(qm)*4+mm_][(qn)*2+nn_] = __builtin_amdgcn_mfma_f32_16x16x32_bf16(        \
            a[mm_][kk_], arr[nn_][kk_], acc[(qm)*4+mm_][(qn)*2+nn_], 0, 0, 0);          \
  } while (0)

#define BAR   __builtin_amdgcn_s_barrier()
#define VM(n) asm volatile("s_waitcnt vmcnt(" #n ")" ::: "memory")
#define LGKM8 asm volatile("s_waitcnt lgkmcnt(8)" ::: "memory")
#define PRIO1 __builtin_amdgcn_s_setprio(1)
#define PRIO0 __builtin_amdgcn_s_setprio(0)

#define PH8(qm, qn, arr, LOADS, STAGES, PREBAR, POSTMFMA) do {                          \
    LOADS;                                                                              \
    STAGES;                                                                             \
    PREBAR;                                                                             \
    BAR;                                                                                \
    asm volatile("s_waitcnt lgkmcnt(0)" ::: "memory");                                  \
    PRIO1;                                                                              \
    MFMAQ(qm, qn, arr);                                                                 \
    PRIO0;                                                                              \
    POSTMFMA;                                                                           \
    BAR;                                                                                \
  } while (0)

__global__ __launch_bounds__(512, 2) void gemm_wz8(const bf16_t* __restrict__ Wb,
                                                   const bf16_t* __restrict__ ZbT,
                                                   bf16_t* __restrict__ OUT_T, int ldn,
                                                   float* __restrict__ ssq) {
  __shared__ __align__(16) bf16_t lds[65536];  // 128 KiB

  int nwg = gridDim.x;
  int bid = blockIdx.x;
  int q = nwg >> 3, r = nwg & 7;
  int xcd = bid & 7, idx = bid >> 3;
  int swz = (xcd < r ? xcd * (q + 1) : r * (q + 1) + (xcd - r) * q) + idx;
  int bm = swz >> 4, bn = swz & 15;   // bn-fastest: co-resident blocks share A panels
  int m0 = bm * 256, n0 = bn * 256;

  int tid = threadIdx.x;
  int wave = tid >> 6, lane = tid & 63;
  int wrow = wave >> 2, wcol = wave & 3;
  int lm = lane & 15, lks = lane >> 4;
  int sw = lm & 7;

  size_t aoff0[2], boff0[2];
  int dstslot[2];
#pragma unroll
  for (int e = 0; e < 2; ++e) {
    int j = e * 512 + tid;
    int rih = j >> 3, sl = j & 7;
    int sg = sl ^ (rih & 7);
    int arow = (rih & 63) + ((rih >> 6) << 7);
    int brow = (rih & 31) + ((rih >> 5) << 6);
    aoff0[e] = (size_t)(m0 + arow) * 1024 + sg * 8;
    boff0[e] = (size_t)(n0 + brow) * 1024 + sg * 8;
    dstslot[e] = e * 4096 + wave * 512;
  }

  int aRowBase = (wrow * 64 + lm) * 64;
  int bRowBase = (wcol * 32 + lm) * 64;
  int sidx[2] = { ((0 + lks) ^ sw) * 8, ((4 + lks) ^ sw) * 8 };

  f32x4 acc[8][4] = {};
  bf16x8 a[4][2], b0[2][2], b1[2][2];

  SA(0, 0, 0); SBst(0, 0, 0); SBst(0, 1, 0); SA(0, 1, 0);
  SA(1, 0, 1); SBst(1, 0, 1); SBst(1, 1, 1);
  VM(6);
  BAR;

  for (int it = 0; it < 8; ++it) {
    int tO = 2 * it + 1, tN = 2 * it + 2, tM = 2 * it + 3;
    bool st = (it < 7);

    PH8(0, 0, b0, LOAD_A(0, 0); LOAD_Bq(0, 0, b0), SA(1, 1, tO), LGKM8, );
    PH8(0, 1, b1, LOAD_Bq(0, 1, b1), { if (st) SA(0, 0, tN); }, , );
    PH8(1, 0, b0, LOAD_A(0, 1), { if (st) SBst(0, 0, tN); }, , );
    PH8(1, 1, b1, , { if (st) SBst(0, 1, tN); }, ,
        { if (st) { VM(6); } else { VM(0); } });
    PH8(0, 0, b0, LOAD_A(1, 0); LOAD_Bq(1, 0, b0), { if (st) SA(0, 1, tN); }, LGKM8, );
    PH8(0, 1, b1, LOAD_Bq(1, 1, b1), { if (st) SA(1, 0, tM); }, , );
    PH8(1, 0, b0, LOAD_A(1, 1), { if (st) SBst(1, 0, tM); }, , );
    PH8(1, 1, b1, , { if (st) SBst(1, 1, tM); }, , { if (st) VM(6); });
  }

#pragma unroll
  for (int mf = 0; mf < 8; ++mf)
#pragma unroll
    for (int nf = 0; nf < 4; ++nf) {
      int col = n0 + wcol * 64 + nf * 16 + lm;
      int row = m0 + wrow * 128 + mf * 16 + lks * 4;
      bf16x4 v;
#pragma unroll
      for (int rr = 0; rr < 4; ++rr) v[rr] = (bf16_t)acc[mf][nf][rr];
      *(bf16x4*)(OUT_T + (size_t)col * M_DIM + row) = v;
    }

  if (m0 < C_CLS * 1024) {
    int c = m0 >> 10;
#pragma unroll
    for (int nf = 0; nf < 4; ++nf) {
      float v = 0.f;
#pragma unroll
      for (int mf = 0; mf < 8; ++mf)
#pragma unroll
        for (int rr = 0; rr < 4; ++rr)
          v += acc[mf][nf][rr] * acc[mf][nf][rr];
      v += __shfl_xor(v, 16);
      v += __shfl_xor(v, 32);
      if (lks == 0)
        atomicAdd(&ssq[(size_t)c * ldn + n0 + wcol * 64 + nf * 16 + lm], v);
    }
  }
}

// ---------------- fat kernel: softmax+update+normalize+ZbT emit (+ pack next layer W) ----------------
__global__ __launch_bounds__(256) void update_pack(const bf16_t* __restrict__ OUT_T, int Nc,
                                                   const float* __restrict__ ssq,
                                                   const float* __restrict__ gamma,
                                                   const float* __restrict__ etap,
                                                   const float* __restrict__ tempr,
                                                   float* __restrict__ ZfT,
                                                   bf16_t* __restrict__ ZbT,
                                                   const float4* __restrict__ CsN,
                                                   const float4* __restrict__ ElN,
                                                   bf16x4* __restrict__ WbN) {
  if (blockIdx.x >= UPD_BLOCKS) {
    pack_body(CsN, ElN, WbN, (blockIdx.x - UPD_BLOCKS) * 256 + threadIdx.x);
    return;
  }
  int wv = threadIdx.x >> 6, lane = threadIdx.x & 63;
  int nl = blockIdx.x * 4 + wv;
  int n = nl;
  float eta = etap[0], invT = 1.0f / tempr[0];

  float s[C_CLS], m = -1e30f;
#pragma unroll
  for (int c = 0; c < C_CLS; ++c) {
    float sim = -sqrtf(ssq[(size_t)c * Nc + nl]);
    s[c] = sim;
    m = fmaxf(m, sim);
  }
  float sum = 0.f;
#pragma unroll
  for (int c = 0; c < C_CLS; ++c) {
    float e = __expf((s[c] - m) * invT);
    s[c] = e;
    sum += e;
  }
  float invsum = 1.0f / sum;
  float gP[C_CLS];
#pragma unroll
  for (int c = 0; c < C_CLS; ++c) gP[c] = gamma[c] * s[c] * invsum;

  const u16x8* ob = (const u16x8*)(OUT_T + (size_t)nl * M_DIM) + lane * 2;
  float term[16] = {};
#pragma unroll
  for (int c = 0; c < C_CLS; ++c) {
    u16x8 v0 = ob[c * 128], v1 = ob[c * 128 + 1];
#pragma unroll
    for (int j = 0; j < 8; ++j) {
      term[j]     += gP[c] * bf2f(v0[j]);
      term[8 + j] += gP[c] * bf2f(v1[j]);
    }
  }
  u16x8 g0 = ob[C_CLS * 128], g1 = ob[C_CLS * 128 + 1];

  const f32x4* zp = (const f32x4*)(ZfT + (size_t)n * D_DIM) + lane * 4;
  f32x4 z[4] = { zp[0], zp[1], zp[2], zp[3] };

  float zn[16];
  float ss = 0.f;
#pragma unroll
  for (int j = 0; j < 16; ++j) {
    float g = bf2f(j < 8 ? g0[j & 7] : g1[j & 7]);
    float v = z[j >> 2][j & 3] + eta * (g - term[j]);
    zn[j] = v;
    ss += v * v;
  }
#pragma unroll
  for (int k = 1; k < 64; k <<= 1) ss += __shfl_xor(ss, k);
  float inv = rsqrtf(ss);

  f32x4* zo = (f32x4*)(ZfT + (size_t)n * D_DIM) + lane * 4;
  bf16x8* bo = (bf16x8*)(ZbT + (size_t)n * D_DIM) + lane * 2;
#pragma unroll
  for (int q4 = 0; q4 < 4; ++q4) {
    f32x4 o;
#pragma unroll
    for (int j = 0; j < 4; ++j) o[j] = zn[q4 * 4 + j] * inv;
    zo[q4] = o;
  }
#pragma unroll
  for (int h = 0; h < 2; ++h) {
    bf16x8 o;
#pragma unroll
    for (int j = 0; j < 8; ++j) o[j] = (bf16_t)(zn[h * 8 + j] * inv);
    bo[h] = o;
  }
}

extern "C" void kernel_launch(void* const* d_in, const int* in_sizes, int n_in,
                              void* d_out, int out_size, void* d_ws, size_t ws_size,
                              hipStream_t stream) {
  (void)in_sizes; (void)n_in; (void)out_size;
  const float* Zin        = (const float*)d_in[0];
  const float* Elist      = (const float*)d_in[1];
  const float* Cslist     = (const float*)d_in[2];
  const float* gamma      = (const float*)d_in[3];
  const float* eta        = (const float*)d_in[4];
  const float* temperature= (const float*)d_in[5];

  auto align256 = [](size_t x) { return (x + 255) & ~(size_t)255; };
  size_t zbt_b = align256((size_t)N_DIM * D_DIM * 2);
  size_t zft_b = align256((size_t)N_DIM * D_DIM * 4);
  size_t wb_b  = align256((size_t)M_DIM * D_DIM * 2);
  size_t ssq_b = align256((size_t)L_IT * C_CLS * N_DIM * 4);
  size_t out_b = align256((size_t)M_DIM * N_DIM * 2);

  if (zbt_b + zft_b + 2 * wb_b + ssq_b + out_b > ws_size) {
    hipMemsetAsync(d_out, 0, (size_t)D_DIM * N_DIM * 4, stream);  // clean-fail signal
    return;
  }

  char* p = (char*)d_ws;
  bf16_t* ZbT  = (bf16_t*)p; p += zbt_b;
  float*  ZfT  = (float*)p;  p += zft_b;
  bf16_t* Wb0  = (bf16_t*)p; p += wb_b;
  bf16_t* Wb1  = (bf16_t*)p; p += wb_b;
  float*  ssq  = (float*)p;  p += ssq_b;
  bf16_t* OUT_T= (bf16_t*)p;
  bf16_t* Wbs[2] = { Wb0, Wb1 };

  hipMemsetAsync(ssq, 0, (size_t)L_IT * C_CLS * N_DIM * 4, stream);

  // init Z (N-major fp32 + bf16) and pack layer-0 W, in one fat kernel
  init_pack<<<dim3(PACK_BLOCKS + 4096), 256, 0, stream>>>(
      Zin, ZfT, ZbT,
      (const float4*)Cslist, (const float4*)Elist, (bf16x4*)Wb0);

  for (int l = 0; l < L_IT; ++l) {
    float* ssq_l = ssq + (size_t)l * C_CLS * N_DIM;
    bf16_t* Wb = Wbs[l & 1];

    gemm_wz8<<<dim3(NBM * (N_DIM / 256)), 512, 0, stream>>>(
        Wb, ZbT, OUT_T, N_DIM, ssq_l);

    if (l + 1 < L_IT) {
      const float* CsN = Cslist + (size_t)(l + 1) * C_CLS * D_DIM * D_DIM;
      const float* ElN = Elist  + (size_t)(l + 1) * D_DIM * D_DIM;
      update_pack<<<dim3(UPD_BLOCKS + PACK_BLOCKS), 256, 0, stream>>>(
          OUT_T, N_DIM, ssq_l, gamma, eta, temperature, ZfT, ZbT,
          (const float4*)CsN, (const float4*)ElN, (bf16x4*)Wbs[(l + 1) & 1]);
    } else {
      update_pack<<<dim3(UPD_BLOCKS), 256, 0, stream>>>(
          OUT_T, N_DIM, ssq_l, gamma, eta, temperature, ZfT, ZbT,
          nullptr, nullptr, nullptr);
    }
  }
  final_out<<<dim3(N_DIM / 32, D_DIM / 32), 256, 0, stream>>>(ZfT, (float*)d_out);
}

// Round 15
// 1142.858 us; speedup vs baseline: 2.2850x; 1.0509x over previous
//
#include <hip/hip_runtime.h>
#include <hip/hip_bf16.h>
#include <hip/hip_fp8.h>
#include <stdint.h>

#define D_DIM 1024
#define N_DIM 4096
#define C_CLS 10
#define L_IT 8
#define M_DIM 11264   // (C+1)*D
#define MC_DIM 10240  // C*D (class rows)
#define NBM 44        // M_DIM / 256
#define PACK_BLOCKS 11264   // M_DIM*D_DIM/4/256
#define UPD_BLOCKS 1024     // N_DIM/4

typedef __bf16 bf16_t;
typedef __bf16 bf16x8 __attribute__((ext_vector_type(8)));
typedef __bf16 bf16x4 __attribute__((ext_vector_type(4)));
typedef float  f32x4  __attribute__((ext_vector_type(4)));
typedef unsigned short u16x8 __attribute__((ext_vector_type(8)));
typedef uint8_t u8x16 __attribute__((ext_vector_type(16)));

__device__ __forceinline__ float bf2f(uint16_t u) {
  union { uint32_t i; float f; } x; x.i = ((uint32_t)u) << 16; return x.f;
}

__device__ __forceinline__ void pack_body(const float4* __restrict__ Cs,
                                          const float4* __restrict__ El,
                                          bf16x4* __restrict__ dst, int i) {
  const int CS4 = C_CLS * D_DIM * D_DIM / 4;
  float4 v = (i < CS4) ? Cs[i] : El[i - CS4];
  bf16x4 o;
  o[0] = (bf16_t)v.x; o[1] = (bf16_t)v.y; o[2] = (bf16_t)v.z; o[3] = (bf16_t)v.w;
  dst[i] = o;
}

// ---------------- fat kernel: layer-0 init (+ pack layer-0 W) ----------------
__global__ __launch_bounds__(256) void init_pack(const float* __restrict__ Zin,
                                                 float* __restrict__ ZfT,
                                                 bf16_t* __restrict__ ZbT,
                                                 const float4* __restrict__ Cs0,
                                                 const float4* __restrict__ El0,
                                                 bf16x4* __restrict__ Wb0) {
  if (blockIdx.x < PACK_BLOCKS) {
    pack_body(Cs0, El0, Wb0, blockIdx.x * 256 + threadIdx.x);
    return;
  }
  int idx = blockIdx.x - PACK_BLOCKS;          // 4096 init blocks
  int nb = idx & 127, db = idx >> 7;           // N/32=128, D/32=32
  __shared__ float tile[32][33];
  int tx = threadIdx.x & 31, ty = threadIdx.x >> 5;
  int n = nb * 32 + tx;
#pragma unroll
  for (int j = 0; j < 32; j += 8) {
    int d = db * 32 + ty + j;
    tile[ty + j][tx] = Zin[(size_t)d * N_DIM + n];
  }
  __syncthreads();
  int d2 = db * 32 + tx;
#pragma unroll
  for (int j = 0; j < 32; j += 8) {
    int n2 = nb * 32 + ty + j;
    float v = tile[tx][ty + j];
    ZfT[(size_t)n2 * D_DIM + d2] = v;
    ZbT[(size_t)n2 * D_DIM + d2] = (bf16_t)v;
  }
}

// ---------------- final transpose-out ----------------
__global__ __launch_bounds__(256) void final_out(const float* __restrict__ ZfT,
                                                 float* __restrict__ outp) {
  __shared__ float tile[32][33];
  int tx = threadIdx.x & 31, ty = threadIdx.x >> 5;
  int nb = blockIdx.x, db = blockIdx.y;
#pragma unroll
  for (int j = 0; j < 32; j += 8) {
    int n = nb * 32 + ty + j;
    int d = db * 32 + tx;
    tile[ty + j][tx] = ZfT[(size_t)n * D_DIM + d];
  }
  __syncthreads();
#pragma unroll
  for (int j = 0; j < 32; j += 8) {
    int d2 = db * 32 + ty + j;
    int n2 = nb * 32 + tx;
    outp[(size_t)d2 * N_DIM + n2] = tile[tx][ty + j];
  }
}

// ================= 256x256 GEMM — m201 8-phase template, 16x16x32 MFMA =================
// Class rows (m0 < 10240) stored fp8 e4m3 scaled x8 into OUTC[col][10240];
// E rows stored bf16 into OUTE[col][1024]. ssq still computed from f32 acc.

#define SA(buf, h, t) do {                                                              \
    _Pragma("unroll") for (int e_ = 0; e_ < 2; ++e_) {                                  \
      const bf16_t* s_ = Wb + aoff0[e_] + (size_t)(h) * 65536 + (size_t)(t) * 64;       \
      __builtin_amdgcn_global_load_lds(                                                 \
        (const __attribute__((address_space(1))) void*)s_,                              \
        (__attribute__((address_space(3))) void*)(lds + (buf)*16384 + (h)*8192 + dstslot[e_]), \
        16, 0, 0);                                                                      \
    } } while (0)

#define SBst(buf, h, t) do {                                                            \
    _Pragma("unroll") for (int e_ = 0; e_ < 2; ++e_) {                                  \
      const bf16_t* s_ = ZbT + boff0[e_] + (size_t)(h) * 32768 + (size_t)(t) * 64;      \
      __builtin_amdgcn_global_load_lds(                                                 \
        (const __attribute__((address_space(1))) void*)s_,                              \
        (__attribute__((address_space(3))) void*)(lds + 32768 + (buf)*16384 + (h)*8192 + dstslot[e_]), \
        16, 0, 0);                                                                      \
    } } while (0)

#define LOAD_A(buf, qm) do {                                                            \
    _Pragma("unroll") for (int f_ = 0; f_ < 4; ++f_)                                    \
      _Pragma("unroll") for (int kk_ = 0; kk_ < 2; ++kk_)                               \
        a[f_][kk_] = *(const bf16x8*)(lds + (buf)*16384 + (qm)*8192 + aRowBase + f_*1024 + sidx[kk_]); \
  } while (0)

#define LOAD_Bq(buf, qn, arr) do {                                                      \
    _Pragma("unroll") for (int f_ = 0; f_ < 2; ++f_)                                    \
      _Pragma("unroll") for (int kk_ = 0; kk_ < 2; ++kk_)                               \
        arr[f_][kk_] = *(const bf16x8*)(lds + 32768 + (buf)*16384 + (qn)*8192 + bRowBase + f_*1024 + sidx[kk_]); \
  } while (0)

#define MFMAQ(qm, qn, arr) do {                                                         \
    _Pragma("unroll") for (int mm_ = 0; mm_ < 4; ++mm_)                                 \
      _Pragma("unroll") for (int nn_ = 0; nn_ < 2; ++nn_)                               \
        _Pragma("unroll") for (int kk_ = 0; kk_ < 2; ++kk_)                             \
          acc[(qm)*4+mm_][(qn)*2+nn_] = __builtin_amdgcn_mfma_f32_16x16x32_bf16(        \
            a[mm_][kk_], arr[nn_][kk_], acc[(qm)*4+mm_][(qn)*2+nn_], 0, 0, 0);          \
  } while (0)

#define BAR   __builtin_amdgcn_s_barrier()
#define VM(n) asm volatile("s_waitcnt vmcnt(" #n ")" ::: "memory")
#define LGKM8 asm volatile("s_waitcnt lgkmcnt(8)" ::: "memory")
#define PRIO1 __builtin_amdgcn_s_setprio(1)
#define PRIO0 __builtin_amdgcn_s_setprio(0)

#define PH8(qm, qn, arr, LOADS, STAGES, PREBAR, POSTMFMA) do {                          \
    LOADS;                                                                              \
    STAGES;                                                                             \
    PREBAR;                                                                             \
    BAR;                                                                                \
    asm volatile("s_waitcnt lgkmcnt(0)" ::: "memory");                                  \
    PRIO1;                                                                              \
    MFMAQ(qm, qn, arr);                                                                 \
    PRIO0;                                                                              \
    POSTMFMA;                                                                           \
    BAR;                                                                                \
  } while (0)

__global__ __launch_bounds__(512, 2) void gemm_wz8(const bf16_t* __restrict__ Wb,
                                                   const bf16_t* __restrict__ ZbT,
                                                   uint8_t* __restrict__ OUTC,
                                                   bf16_t* __restrict__ OUTE,
                                                   int ldn,
                                                   float* __restrict__ ssq) {
  __shared__ __align__(16) bf16_t lds[65536];  // 128 KiB

  int nwg = gridDim.x;
  int bid = blockIdx.x;
  int q = nwg >> 3, r = nwg & 7;
  int xcd = bid & 7, idx = bid >> 3;
  int swz = (xcd < r ? xcd * (q + 1) : r * (q + 1) + (xcd - r) * q) + idx;
  int bm = swz >> 4, bn = swz & 15;   // bn-fastest: co-resident blocks share A panels
  int m0 = bm * 256, n0 = bn * 256;

  int tid = threadIdx.x;
  int wave = tid >> 6, lane = tid & 63;
  int wrow = wave >> 2, wcol = wave & 3;
  int lm = lane & 15, lks = lane >> 4;
  int sw = lm & 7;

  size_t aoff0[2], boff0[2];
  int dstslot[2];
#pragma unroll
  for (int e = 0; e < 2; ++e) {
    int j = e * 512 + tid;
    int rih = j >> 3, sl = j & 7;
    int sg = sl ^ (rih & 7);
    int arow = (rih & 63) + ((rih >> 6) << 7);
    int brow = (rih & 31) + ((rih >> 5) << 6);
    aoff0[e] = (size_t)(m0 + arow) * 1024 + sg * 8;
    boff0[e] = (size_t)(n0 + brow) * 1024 + sg * 8;
    dstslot[e] = e * 4096 + wave * 512;
  }

  int aRowBase = (wrow * 64 + lm) * 64;
  int bRowBase = (wcol * 32 + lm) * 64;
  int sidx[2] = { ((0 + lks) ^ sw) * 8, ((4 + lks) ^ sw) * 8 };

  f32x4 acc[8][4] = {};
  bf16x8 a[4][2], b0[2][2], b1[2][2];

  SA(0, 0, 0); SBst(0, 0, 0); SBst(0, 1, 0); SA(0, 1, 0);
  SA(1, 0, 1); SBst(1, 0, 1); SBst(1, 1, 1);
  VM(6);
  BAR;

  for (int it = 0; it < 8; ++it) {
    int tO = 2 * it + 1, tN = 2 * it + 2, tM = 2 * it + 3;
    bool st = (it < 7);

    PH8(0, 0, b0, LOAD_A(0, 0); LOAD_Bq(0, 0, b0), SA(1, 1, tO), LGKM8, );
    PH8(0, 1, b1, LOAD_Bq(0, 1, b1), { if (st) SA(0, 0, tN); }, , );
    PH8(1, 0, b0, LOAD_A(0, 1), { if (st) SBst(0, 0, tN); }, , );
    PH8(1, 1, b1, , { if (st) SBst(0, 1, tN); }, ,
        { if (st) { VM(6); } else { VM(0); } });
    PH8(0, 0, b0, LOAD_A(1, 0); LOAD_Bq(1, 0, b0), { if (st) SA(0, 1, tN); }, LGKM8, );
    PH8(0, 1, b1, LOAD_Bq(1, 1, b1), { if (st) SA(1, 0, tM); }, , );
    PH8(1, 0, b0, LOAD_A(1, 1), { if (st) SBst(1, 0, tM); }, , );
    PH8(1, 1, b1, , { if (st) SBst(1, 1, tM); }, , { if (st) VM(6); });
  }

  if (m0 < MC_DIM) {
    // class rows: fp8 e4m3, scaled x8; 4 rows pack into one dword store
#pragma unroll
    for (int mf = 0; mf < 8; ++mf)
#pragma unroll
      for (int nf = 0; nf < 4; ++nf) {
        int col = n0 + wcol * 64 + nf * 16 + lm;
        int row = m0 + wrow * 128 + mf * 16 + lks * 4;
        uint32_t pk = 0;
#pragma unroll
        for (int rr = 0; rr < 4; ++rr) {
          __hip_fp8_e4m3 qv(acc[mf][nf][rr] * 8.0f);
          pk |= (uint32_t)qv.__x << (8 * rr);
        }
        *(uint32_t*)(OUTC + (size_t)col * MC_DIM + row) = pk;
      }
    // fused per-class column sum-of-squares (from f32 acc — full precision)
    int c = m0 >> 10;
#pragma unroll
    for (int nf = 0; nf < 4; ++nf) {
      float v = 0.f;
#pragma unroll
      for (int mf = 0; mf < 8; ++mf)
#pragma unroll
        for (int rr = 0; rr < 4; ++rr)
          v += acc[mf][nf][rr] * acc[mf][nf][rr];
      v += __shfl_xor(v, 16);
      v += __shfl_xor(v, 32);
      if (lks == 0)
        atomicAdd(&ssq[(size_t)c * ldn + n0 + wcol * 64 + nf * 16 + lm], v);
    }
  } else {
    // E rows: bf16
#pragma unroll
    for (int mf = 0; mf < 8; ++mf)
#pragma unroll
      for (int nf = 0; nf < 4; ++nf) {
        int col = n0 + wcol * 64 + nf * 16 + lm;
        int row = (m0 - MC_DIM) + wrow * 128 + mf * 16 + lks * 4;
        bf16x4 v;
#pragma unroll
        for (int rr = 0; rr < 4; ++rr) v[rr] = (bf16_t)acc[mf][nf][rr];
        *(bf16x4*)(OUTE + (size_t)col * D_DIM + row) = v;
      }
  }
}

// ---------------- fat kernel: softmax+update+normalize+ZbT emit (+ pack next layer W) ----------------
__global__ __launch_bounds__(256) void update_pack(const uint8_t* __restrict__ OUTC,
                                                   const bf16_t* __restrict__ OUTE,
                                                   int Nc,
                                                   const float* __restrict__ ssq,
                                                   const float* __restrict__ gamma,
                                                   const float* __restrict__ etap,
                                                   const float* __restrict__ tempr,
                                                   float* __restrict__ ZfT,
                                                   bf16_t* __restrict__ ZbT,
                                                   const float4* __restrict__ CsN,
                                                   const float4* __restrict__ ElN,
                                                   bf16x4* __restrict__ WbN) {
  if (blockIdx.x >= UPD_BLOCKS) {
    pack_body(CsN, ElN, WbN, (blockIdx.x - UPD_BLOCKS) * 256 + threadIdx.x);
    return;
  }
  int wv = threadIdx.x >> 6, lane = threadIdx.x & 63;
  int nl = blockIdx.x * 4 + wv;
  int n = nl;
  float eta = etap[0], invT = 1.0f / tempr[0];

  float s[C_CLS], m = -1e30f;
#pragma unroll
  for (int c = 0; c < C_CLS; ++c) {
    float sim = -sqrtf(ssq[(size_t)c * Nc + nl]);
    s[c] = sim;
    m = fmaxf(m, sim);
  }
  float sum = 0.f;
#pragma unroll
  for (int c = 0; c < C_CLS; ++c) {
    float e = __expf((s[c] - m) * invT);
    s[c] = e;
    sum += e;
  }
  float invsum = 0.125f / sum;   // fold the 1/8 fp8 scale into gP
  float gP[C_CLS];
#pragma unroll
  for (int c = 0; c < C_CLS; ++c) gP[c] = gamma[c] * s[c] * invsum;

  // lane owns rows i = lane*16 .. lane*16+15
  const uint8_t* ocb = OUTC + (size_t)nl * MC_DIM + lane * 16;
  float term[16] = {};
#pragma unroll
  for (int c = 0; c < C_CLS; ++c) {
    u8x16 v = *(const u8x16*)(ocb + c * 1024);
#pragma unroll
    for (int j = 0; j < 16; ++j) {
      __hip_fp8_e4m3 t; t.__x = v[j];
      term[j] += gP[c] * (float)t;
    }
  }
  const u16x8* oe = (const u16x8*)(OUTE + (size_t)nl * D_DIM) + lane * 2;
  u16x8 g0 = oe[0], g1 = oe[1];

  const f32x4* zp = (const f32x4*)(ZfT + (size_t)n * D_DIM) + lane * 4;
  f32x4 z[4] = { zp[0], zp[1], zp[2], zp[3] };

  float zn[16];
  float ss = 0.f;
#pragma unroll
  for (int j = 0; j < 16; ++j) {
    float g = bf2f(j < 8 ? g0[j & 7] : g1[j & 7]);
    float v = z[j >> 2][j & 3] + eta * (g - term[j]);
    zn[j] = v;
    ss += v * v;
  }
#pragma unroll
  for (int k = 1; k < 64; k <<= 1) ss += __shfl_xor(ss, k);
  float inv = rsqrtf(ss);

  f32x4* zo = (f32x4*)(ZfT + (size_t)n * D_DIM) + lane * 4;
  bf16x8* bo = (bf16x8*)(ZbT + (size_t)n * D_DIM) + lane * 2;
#pragma unroll
  for (int q4 = 0; q4 < 4; ++q4) {
    f32x4 o;
#pragma unroll
    for (int j = 0; j < 4; ++j) o[j] = zn[q4 * 4 + j] * inv;
    zo[q4] = o;
  }
#pragma unroll
  for (int h = 0; h < 2; ++h) {
    bf16x8 o;
#pragma unroll
    for (int j = 0; j < 8; ++j) o[j] = (bf16_t)(zn[h * 8 + j] * inv);
    bo[h] = o;
  }
}

extern "C" void kernel_launch(void* const* d_in, const int* in_sizes, int n_in,
                              void* d_out, int out_size, void* d_ws, size_t ws_size,
                              hipStream_t stream) {
  (void)in_sizes; (void)n_in; (void)out_size;
  const float* Zin        = (const float*)d_in[0];
  const float* Elist      = (const float*)d_in[1];
  const float* Cslist     = (const float*)d_in[2];
  const float* gamma      = (const float*)d_in[3];
  const float* eta        = (const float*)d_in[4];
  const float* temperature= (const float*)d_in[5];

  auto align256 = [](size_t x) { return (x + 255) & ~(size_t)255; };
  size_t zbt_b = align256((size_t)N_DIM * D_DIM * 2);
  size_t zft_b = align256((size_t)N_DIM * D_DIM * 4);
  size_t wb_b  = align256((size_t)M_DIM * D_DIM * 2);
  size_t ssq_b = align256((size_t)L_IT * C_CLS * N_DIM * 4);
  size_t outc_b= align256((size_t)N_DIM * MC_DIM * 1);
  size_t oute_b= align256((size_t)N_DIM * D_DIM * 2);

  if (zbt_b + zft_b + 2 * wb_b + ssq_b + outc_b + oute_b > ws_size) {
    hipMemsetAsync(d_out, 0, (size_t)D_DIM * N_DIM * 4, stream);  // clean-fail signal
    return;
  }

  char* p = (char*)d_ws;
  bf16_t* ZbT  = (bf16_t*)p; p += zbt_b;
  float*  ZfT  = (float*)p;  p += zft_b;
  bf16_t* Wb0  = (bf16_t*)p; p += wb_b;
  bf16_t* Wb1  = (bf16_t*)p; p += wb_b;
  float*  ssq  = (float*)p;  p += ssq_b;
  uint8_t* OUTC= (uint8_t*)p; p += outc_b;
  bf16_t* OUTE = (bf16_t*)p;
  bf16_t* Wbs[2] = { Wb0, Wb1 };

  hipMemsetAsync(ssq, 0, (size_t)L_IT * C_CLS * N_DIM * 4, stream);

  init_pack<<<dim3(PACK_BLOCKS + 4096), 256, 0, stream>>>(
      Zin, ZfT, ZbT,
      (const float4*)Cslist, (const float4*)Elist, (bf16x4*)Wb0);

  for (int l = 0; l < L_IT; ++l) {
    float* ssq_l = ssq + (size_t)l * C_CLS * N_DIM;
    bf16_t* Wb = Wbs[l & 1];

    gemm_wz8<<<dim3(NBM * (N_DIM / 256)), 512, 0, stream>>>(
        Wb, ZbT, OUTC, OUTE, N_DIM, ssq_l);

    if (l + 1 < L_IT) {
      const float* CsN = Cslist + (size_t)(l + 1) * C_CLS * D_DIM * D_DIM;
      const float* ElN = Elist  + (size_t)(l + 1) * D_DIM * D_DIM;
      update_pack<<<dim3(UPD_BLOCKS + PACK_BLOCKS), 256, 0, stream>>>(
          OUTC, OUTE, N_DIM, ssq_l, gamma, eta, temperature, ZfT, ZbT,
          (const float4*)CsN, (const float4*)ElN, (bf16x4*)Wbs[(l + 1) & 1]);
    } else {
      update_pack<<<dim3(UPD_BLOCKS), 256, 0, stream>>>(
          OUTC, OUTE, N_DIM, ssq_l, gamma, eta, temperature, ZfT, ZbT,
          nullptr, nullptr, nullptr);
    }
  }
  final_out<<<dim3(N_DIM / 32, D_DIM / 32), 256, 0, stream>>>(ZfT, (float*)d_out);
}